// Round 4
// baseline (1237.202 us; speedup 1.0000x reference)
//
#include <hip/hip_runtime.h>

#define BB 8192
#define TT 20
#define HH 128
#define H4 512
#define KC 5
#define ROWS 8
#define NT 128

// output segment offsets (elements)
#define GY_OFF (BB*TT*30)
#define GF_OFF (GY_OFF + BB*TT*15)
#define GFA_OFF (GF_OFF + BB*TT*15)

__device__ __forceinline__ float sigm(float x){ return 1.0f / (1.0f + __expf(-x)); }
__device__ __forceinline__ float tanh_(float x){
    x = fminf(10.0f, fmaxf(-10.0f, x));
    float e = __expf(2.0f * x);
    return (e - 1.0f) / (e + 1.0f);
}

#define AM0 0.3f
#define AM1 0.1f
#define AO  0.3f

__global__ __launch_bounds__(NT) void decoder_kernel(
    const float* __restrict__ cond_m, const float* __restrict__ cond_y,
    const float* __restrict__ cond_f, const float* __restrict__ cond_fa,
    const float* __restrict__ state_h, const float* __restrict__ state_c,
    const float* __restrict__ W_my, const float* __restrict__ U_my, const float* __restrict__ b_my,
    const float* __restrict__ W_ff, const float* __restrict__ U_ff, const float* __restrict__ b_ff,
    const float* __restrict__ Wh_my, const float* __restrict__ bh_my,
    const float* __restrict__ Wh_ff, const float* __restrict__ bh_ff,
    const float* __restrict__ gum, const float* __restrict__ znorm,
    float* __restrict__ out)
{
    // h lives in LDS as [k][r]; c lives in registers of the thread owning hidden idx j
    __shared__ float s_hm[HH][ROWS];
    __shared__ float s_hf[HH][ROWS];
    __shared__ float s_r[ROWS][76];     // r_my[0..44], r_ff[45..74]
    __shared__ float s_red[ROWS][8];    // 4 softmax groups x (max, 1/sum)
    __shared__ float s_c5[ROWS][5];
    __shared__ float s_c2[ROWS][2];

    const int j    = threadIdx.x;        // this thread's gate-column (0..127)
    const int row0 = blockIdx.x * ROWS;

    // ---- init h (LDS), c (regs), cond (LDS) ----
    for (int p = j; p < HH*ROWS; p += NT){
        int k = p >> 3, r = p & 7;
        float hv = state_h[(row0 + r)*HH + k];
        s_hm[k][r] = hv;
        s_hf[k][r] = hv;
    }
    float c_my[ROWS], c_ff[ROWS];
    #pragma unroll
    for (int r = 0; r < ROWS; r++){
        float cv = state_c[(row0 + r)*HH + j];
        c_my[r] = cv; c_ff[r] = cv;
    }
    if (j < ROWS){
        int b = row0 + j;
        float m0 = cond_m[(b*TT)*2 + 0];
        float m1 = cond_m[(b*TT)*2 + 1];
        float y0 = cond_y[b*TT];
        float f0 = cond_f[b*TT];
        float fa0= cond_fa[b*TT];
        s_c5[j][0]=m0; s_c5[j][1]=m1; s_c5[j][2]=y0; s_c5[j][3]=f0; s_c5[j][4]=fa0;
        s_c2[j][0]=f0; s_c2[j][1]=fa0;
    }
    __syncthreads();

    // ---- pre[gate][r] = b[j+gate*128] + sum_k enc_h[r][k] * W[k][j+gate*128] ----
    float pm[4][ROWS], pf[4][ROWS];
    #pragma unroll
    for (int g = 0; g < 4; g++){
        float bm = b_my[j + g*HH];
        float bf = b_ff[j + g*HH];
        #pragma unroll
        for (int r = 0; r < ROWS; r++){ pm[g][r] = bm; pf[g][r] = bf; }
    }
    for (int k = 0; k < HH; k++){
        const float* wm = W_my + k*H4 + j;
        const float* wf = W_ff + k*H4 + j;
        float wm0 = wm[0], wm1 = wm[HH], wm2 = wm[2*HH], wm3 = wm[3*HH];
        float wf0 = wf[0], wf1 = wf[HH], wf2 = wf[2*HH], wf3 = wf[3*HH];
        #pragma unroll
        for (int r = 0; r < ROWS; r++){
            float e = s_hm[k][r];            // enc_h (initial state)
            pm[0][r] = fmaf(e, wm0, pm[0][r]);
            pm[1][r] = fmaf(e, wm1, pm[1][r]);
            pm[2][r] = fmaf(e, wm2, pm[2][r]);
            pm[3][r] = fmaf(e, wm3, pm[3][r]);
            pf[0][r] = fmaf(e, wf0, pf[0][r]);
            pf[1][r] = fmaf(e, wf1, pf[1][r]);
            pf[2][r] = fmaf(e, wf2, pf[2][r]);
            pf[3][r] = fmaf(e, wf3, pf[3][r]);
        }
    }

    const float* Wc_my = W_my + HH*H4;   // cond rows 128..132
    const float* Wc_ff = W_ff + HH*H4;   // cond rows 128..129

    for (int t = 0; t < TT; t++){
        float z[4][ROWS];

        // ================= LSTM my =================
        #pragma unroll
        for (int g = 0; g < 4; g++)
            #pragma unroll
            for (int r = 0; r < ROWS; r++) z[g][r] = pm[g][r];
        for (int k = 0; k < 5; k++){
            const float* w = Wc_my + k*H4 + j;
            float w0 = w[0], w1 = w[HH], w2 = w[2*HH], w3 = w[3*HH];
            #pragma unroll
            for (int r = 0; r < ROWS; r++){
                float cv = s_c5[r][k];
                z[0][r] = fmaf(cv, w0, z[0][r]);
                z[1][r] = fmaf(cv, w1, z[1][r]);
                z[2][r] = fmaf(cv, w2, z[2][r]);
                z[3][r] = fmaf(cv, w3, z[3][r]);
            }
        }
        for (int k = 0; k < HH; k++){
            const float* u = U_my + k*H4 + j;
            float u0 = u[0], u1 = u[HH], u2 = u[2*HH], u3 = u[3*HH];
            #pragma unroll
            for (int r = 0; r < ROWS; r++){
                float hv = s_hm[k][r];
                z[0][r] = fmaf(hv, u0, z[0][r]);
                z[1][r] = fmaf(hv, u1, z[1][r]);
                z[2][r] = fmaf(hv, u2, z[2][r]);
                z[3][r] = fmaf(hv, u3, z[3][r]);
            }
        }
        __syncthreads();   // all reads of s_hm complete
        #pragma unroll
        for (int r = 0; r < ROWS; r++){
            float c2 = sigm(z[1][r])*c_my[r] + sigm(z[0][r])*tanh_(z[2][r]);
            c_my[r] = c2;
            s_hm[j][r] = sigm(z[3][r])*tanh_(c2);
        }

        // ================= LSTM ff =================
        #pragma unroll
        for (int g = 0; g < 4; g++)
            #pragma unroll
            for (int r = 0; r < ROWS; r++) z[g][r] = pf[g][r];
        for (int k = 0; k < 2; k++){
            const float* w = Wc_ff + k*H4 + j;
            float w0 = w[0], w1 = w[HH], w2 = w[2*HH], w3 = w[3*HH];
            #pragma unroll
            for (int r = 0; r < ROWS; r++){
                float cv = s_c2[r][k];
                z[0][r] = fmaf(cv, w0, z[0][r]);
                z[1][r] = fmaf(cv, w1, z[1][r]);
                z[2][r] = fmaf(cv, w2, z[2][r]);
                z[3][r] = fmaf(cv, w3, z[3][r]);
            }
        }
        for (int k = 0; k < HH; k++){
            const float* u = U_ff + k*H4 + j;
            float u0 = u[0], u1 = u[HH], u2 = u[2*HH], u3 = u[3*HH];
            #pragma unroll
            for (int r = 0; r < ROWS; r++){
                float hv = s_hf[k][r];
                z[0][r] = fmaf(hv, u0, z[0][r]);
                z[1][r] = fmaf(hv, u1, z[1][r]);
                z[2][r] = fmaf(hv, u2, z[2][r]);
                z[3][r] = fmaf(hv, u3, z[3][r]);
            }
        }
        __syncthreads();   // all reads of s_hf complete (and s_hm writes visible)
        #pragma unroll
        for (int r = 0; r < ROWS; r++){
            float c2 = sigm(z[1][r])*c_ff[r] + sigm(z[0][r])*tanh_(z[2][r]);
            c_ff[r] = c2;
            s_hf[j][r] = sigm(z[3][r])*tanh_(c2);
        }
        __syncthreads();   // s_hf visible

        // ================= heads =================
        for (int idx = j; idx < ROWS*45 + ROWS*30; idx += NT){
            if (idx < ROWS*45){
                int r = idx / 45, cc = idx % 45;
                float acc = bh_my[cc];
                for (int k = 0; k < HH; k++)
                    acc = fmaf(s_hm[k][r], Wh_my[k*45 + cc], acc);
                s_r[r][cc] = acc;
            } else {
                int i2 = idx - ROWS*45;
                int r = i2 / 30, cc = i2 % 30;
                float acc = bh_ff[cc];
                for (int k = 0; k < HH; k++)
                    acc = fmaf(s_hf[k][r], Wh_ff[k*30 + cc], acc);
                s_r[r][45 + cc] = acc;
            }
        }
        __syncthreads();

        // softmax reductions: r_my bases {0,30}, r_ff bases {45,60}
        if (j < ROWS*4){
            int r = j >> 2, g = j & 3;
            int base = (g==0) ? 0 : (g==1) ? 30 : (g==2) ? 45 : 60;
            float m = s_r[r][base];
            #pragma unroll
            for (int k = 1; k < KC; k++) m = fmaxf(m, s_r[r][base+k]);
            float s = 0.f;
            #pragma unroll
            for (int k = 0; k < KC; k++) s += __expf(s_r[r][base+k] - m);
            s_red[r][2*g] = m; s_red[r][2*g+1] = 1.0f / s;
        }
        __syncthreads();

        // ================= outputs (fp32) =================
        for (int idx = j; idx < ROWS*75; idx += NT){
            int r = idx / 75, q = idx % 75;
            int b = row0 + r;
            float v; int dst;
            if (q < 30){
                float x = s_r[r][q];
                if (q < 5)       v = __expf(x - s_red[r][0]) * s_red[r][1];
                else if (q < 10) v = x;
                else if (q < 15) v = __expf(x);
                else if (q < 20) v = x;
                else if (q < 25) v = __expf(x);
                else             v = tanh_(x);
                dst = (b*TT + t)*30 + q;
            } else if (q < 45){
                int q2 = q - 30; float x = s_r[r][30 + q2];
                v = (q2 < 5) ? __expf(x - s_red[r][2]) * s_red[r][3]
                             : (q2 < 10) ? x : __expf(x);
                dst = GY_OFF + (b*TT + t)*15 + q2;
            } else if (q < 60){
                int q2 = q - 45; float x = s_r[r][45 + q2];
                v = (q2 < 5) ? __expf(x - s_red[r][4]) * s_red[r][5]
                             : (q2 < 10) ? x : __expf(x);
                dst = GF_OFF + (b*TT + t)*15 + q2;
            } else {
                int q2 = q - 60; float x = s_r[r][60 + q2];
                v = (q2 < 5) ? __expf(x - s_red[r][6]) * s_red[r][7]
                             : (q2 < 10) ? x : __expf(x);
                dst = GFA_OFF + (b*TT + t)*15 + q2;
            }
            out[dst] = v;
        }

        // ================= sampling + next cond =================
        if (j < ROWS){
            int r = j, b = row0 + r;
            int tn = (t + 1 < TT) ? t + 1 : TT - 1;
            const float* R = s_r[r];
            const float* g0 = gum + ((t*4 + 0)*BB + b)*KC;
            const float* g1 = gum + ((t*4 + 1)*BB + b)*KC;
            const float* g2 = gum + ((t*4 + 2)*BB + b)*KC;
            const float* g3 = gum + ((t*4 + 3)*BB + b)*KC;
            const float* zn = znorm + (t*BB + b)*5;

            // argmax_k (logit_k + gumbel_k)  == argmax(log softmax + g)
            int im = 0;  { float bv = R[0] + g0[0];
                for (int k = 1; k < KC; k++){ float v = R[k] + g0[k]; if (v > bv){ bv = v; im = k; } } }
            int iy = 0;  { float bv = R[30] + g1[0];
                for (int k = 1; k < KC; k++){ float v = R[30+k] + g1[k]; if (v > bv){ bv = v; iy = k; } } }
            int if_ = 0; { float bv = R[45] + g2[0];
                for (int k = 1; k < KC; k++){ float v = R[45+k] + g2[k]; if (v > bv){ bv = v; if_ = k; } } }
            int ifa = 0; { float bv = R[60] + g3[0];
                for (int k = 1; k < KC; k++){ float v = R[60+k] + g3[k]; if (v > bv){ bv = v; ifa = k; } } }

            float z1 = zn[0], z2 = zn[1];
            float rv   = tanh_(R[25 + im]);
            float slon = R[5 + im]  + __expf(R[10 + im]) * z1;
            float slat = R[15 + im] + __expf(R[20 + im]) *
                         (rv*z1 + sqrtf(fmaxf(0.f, 1.f - rv*rv))*z2);
            float sy  = R[35 + iy]  + __expf(R[40 + iy])  * zn[2];
            float sf  = R[50 + if_] + __expf(R[55 + if_]) * zn[3];
            float sfa = R[65 + ifa] + __expf(R[70 + ifa]) * zn[4];

            float nm0 = cond_m[(b*TT + tn)*2 + 0];
            float nm1 = cond_m[(b*TT + tn)*2 + 1];
            float ny  = cond_y[b*TT + tn];
            float nf  = cond_f[b*TT + tn];
            float nfa = cond_fa[b*TT + tn];

            float cm0 = (fabsf(slon - nm0) < AM0) ? slon : nm0;
            float cm1 = (fabsf(slat - nm1) < AM1) ? slat : nm1;
            float cy  = (fabsf(sy  - ny ) < AO ) ? sy  : ny;
            float cf  = (fabsf(sf  - nf ) < AO ) ? sf  : nf;
            float cfa = (fabsf(sfa - nfa) < AO ) ? sfa : nfa;

            s_c5[r][0] = cm0; s_c5[r][1] = cm1; s_c5[r][2] = cy;
            s_c5[r][3] = cf;  s_c5[r][4] = cfa;
            s_c2[r][0] = cf;  s_c2[r][1] = cfa;
        }
        __syncthreads();   // s_c5/s_c2 ready for next step
    }
}

extern "C" void kernel_launch(void* const* d_in, const int* in_sizes, int n_in,
                              void* d_out, int out_size, void* d_ws, size_t ws_size,
                              hipStream_t stream)
{
    (void)in_sizes; (void)n_in; (void)d_ws; (void)ws_size; (void)out_size;
    const float* cond_m  = (const float*)d_in[0];
    const float* cond_y  = (const float*)d_in[1];
    const float* cond_f  = (const float*)d_in[2];
    const float* cond_fa = (const float*)d_in[3];
    const float* state_h = (const float*)d_in[4];
    const float* state_c = (const float*)d_in[5];
    const float* W_my    = (const float*)d_in[6];
    const float* U_my    = (const float*)d_in[7];
    const float* b_my    = (const float*)d_in[8];
    const float* W_ff    = (const float*)d_in[9];
    const float* U_ff    = (const float*)d_in[10];
    const float* b_ff    = (const float*)d_in[11];
    const float* Wh_my   = (const float*)d_in[12];
    const float* bh_my   = (const float*)d_in[13];
    const float* Wh_ff   = (const float*)d_in[14];
    const float* bh_ff   = (const float*)d_in[15];
    const float* gum     = (const float*)d_in[16];
    const float* znorm   = (const float*)d_in[17];
    float* out = (float*)d_out;

    decoder_kernel<<<BB/ROWS, NT, 0, stream>>>(
        cond_m, cond_y, cond_f, cond_fa, state_h, state_c,
        W_my, U_my, b_my, W_ff, U_ff, b_ff,
        Wh_my, bh_my, Wh_ff, bh_ff, gum, znorm, out);
}